// Round 8
// baseline (454.828 us; speedup 1.0000x reference)
//
#include <hip/hip_runtime.h>

#define NPTS  32768
#define DIM   256

#define ZQ_OFF   0
#define LOSS_OFF 8388608
#define IDX_OFF  8388609

typedef __attribute__((ext_vector_type(8))) short short8;
typedef __attribute__((ext_vector_type(4))) float f32x4;
typedef unsigned short ushort_t;
typedef unsigned int u32;
typedef unsigned long long u64;

#define ZXP 20   // zx row pad (floats): float4-aligned stores, conflict-free reads

// z layout [B, D, H, W]: point n = b*1024 + h*32 + w ; elem (n,d) at b*262144 + d*1024 + hw
__device__ __forceinline__ int z_base(int n) { return ((n >> 10) << 18) | (n & 1023); }

// RNE float->bf16 (bits)
__device__ __forceinline__ ushort_t f2bf(float f) {
    u32 u = __float_as_uint(f);
    u += 0x7FFFu + ((u >> 16) & 1u);
    return (ushort_t)(u >> 16);
}

__device__ __forceinline__ u64 pack_vi(float v, int i) {
    u32 u = __float_as_uint(v);
    u32 key = (u & 0x80000000u) ? ~u : u;   // monotone float->uint (finite)
    return ((u64)key << 32) | (u32)i;
}

// ---- numpy pairwise sum (AVX512 npyv order) of squares, 128 elems ----
__device__ __forceinline__ float np_half_sq(const float* __restrict__ p, int stride) {
    float S[16];
#pragma unroll
    for (int l = 0; l < 16; ++l) {
        float t[8];
#pragma unroll
        for (int j = 0; j < 8; ++j) {
            float v = p[(j * 16 + l) * stride];
            t[j] = __fmul_rn(v, v);
        }
        S[l] = __fadd_rn(__fadd_rn(__fadd_rn(t[0], t[1]), __fadd_rn(t[2], t[3])),
                         __fadd_rn(__fadd_rn(t[4], t[5]), __fadd_rn(t[6], t[7])));
    }
    float u[8];
#pragma unroll
    for (int i = 0; i < 8; ++i) u[i] = __fadd_rn(S[i], S[i + 8]);
    float v4[4];
#pragma unroll
    for (int i = 0; i < 4; ++i) v4[i] = __fadd_rn(u[i], u[i + 4]);
    return __fadd_rn(__fadd_rn(v4[0], v4[2]), __fadd_rn(v4[1], v4[3]));
}
__device__ __forceinline__ float np_sum256_sq(const float* __restrict__ p, int stride) {
    return __fadd_rn(np_half_sq(p, stride), np_half_sq(p + 128 * stride, stride));
}

// same square chain (bit-identical half-sum), abs-sum fused (order-free bound input)
__device__ __forceinline__ float np_half_sq_abs(const float* __restrict__ p, int stride, float* aacc) {
    float S[16]; float a = *aacc;
#pragma unroll
    for (int l = 0; l < 16; ++l) {
        float t[8];
#pragma unroll
        for (int j = 0; j < 8; ++j) {
            float v = p[(j * 16 + l) * stride];
            t[j] = __fmul_rn(v, v);
            a = __fadd_rn(a, fabsf(v));
        }
        S[l] = __fadd_rn(__fadd_rn(__fadd_rn(t[0], t[1]), __fadd_rn(t[2], t[3])),
                         __fadd_rn(__fadd_rn(t[4], t[5]), __fadd_rn(t[6], t[7])));
    }
    float u[8];
#pragma unroll
    for (int i = 0; i < 8; ++i) u[i] = __fadd_rn(S[i], S[i + 8]);
    float v4[4];
#pragma unroll
    for (int i = 0; i < 4; ++i) v4[i] = __fadd_rn(u[i], u[i + 4]);
    *aacc = a;
    return __fadd_rn(__fadd_rn(v4[0], v4[2]), __fadd_rn(v4[1], v4[3]));
}

// blocks 0..255: z2/eps/bestG, 128 points per block, one thread per point (full np chain).
// blocks 256..271: e2/e2h + FRAGMENT-TILED bf16 image of emb:
//   fragment f = kt*16 + nt*8 + dt is a 1KB block; slot l holds
//   bf16 emb[kt*32+nt*16+(l&15)][dt*32+(l>>4)*8 .. +7] at f*1024 + l*16.
__global__ __launch_bounds__(256) void setup_kernel(
    const float* __restrict__ z, const float* __restrict__ emb,
    float* __restrict__ z2, float* __restrict__ eps,
    float* __restrict__ e2, float* __restrict__ e2h,
    ushort_t* __restrict__ ebf, u64* __restrict__ bestG,
    double* __restrict__ loss_acc, unsigned int* __restrict__ ticket)
{
    if (blockIdx.x < 256) {
        if (threadIdx.x < 128) {
            int n = blockIdx.x * 128 + threadIdx.x;
            const float* p = z + z_base(n);
            float a = 0.0f;
            float h0 = np_half_sq_abs(p, 1024, &a);
            float h1 = np_half_sq_abs(p + 128 * 1024, 1024, &a);
            z2[n] = __fadd_rn(h0, h1);
            eps[n] = __builtin_fmaf(1e-5f, a, 3e-4f);   // sound |d~ - d| bound
            bestG[n] = 0x7FFFFFFFFFFFFFFFULL;
        }
        if (blockIdx.x == 0 && threadIdx.x == 0) { *loss_acc = 0.0; *ticket = 0u; }
    } else {
        int kb = (blockIdx.x - 256) * 64;                // 64 emb rows per block
        for (int i = threadIdx.x; i < 2048; i += 256) {
            int klocal = i >> 5, c = i & 31;             // c = dt*4 + lq
            int k = kb + klocal;
            int dt = c >> 2, lq = c & 3;
            int kt = k >> 5, nt = (k >> 4) & 1, lr = k & 15;
            const float* e = emb + k * 256 + dt * 32 + lq * 8;
            short8 ov;
#pragma unroll
            for (int j = 0; j < 8; ++j) ov[j] = (short)f2bf(e[j]);
            int f = kt * 16 + nt * 8 + dt;
            *(short8*)(ebf + (f << 9) + ((lq << 4) + lr) * 8) = ov;
        }
        if (threadIdx.x < 64) {
            int k = kb + threadIdx.x;
            float s = np_sum256_sq(emb + k * DIM, 1);
            e2[k] = s;
            e2h[k] = 0.5f * s;
        }
    }
}

// ---------------- MFMA distance + candidate filter + exact recheck ----------------
// 2048 blocks: 16 pts each; 4 waves = 4 K-QUARTERS (256 k each) of the SAME 16 points.
// Grid 8 blocks/CU -> the occupancy that R3..R7 (512-block grids, 2/CU) never had.
// Barrier-free, LDS-free main loop; A gathered once (32 VGPR); B direct global->VGPR
// (1 coalesced dwordx4 per fragment), register double-buffer prefetch depth 2.
// Per-wave running max over its quarter: thr_local <= thr_global -> superset, sound.
__global__ __launch_bounds__(256, 4) void dist_kernel(
    const float* __restrict__ z, const float* __restrict__ emb,
    const ushort_t* __restrict__ ebf,
    const float* __restrict__ z2w, const float* __restrict__ e2w,
    const float* __restrict__ e2hw, const float* __restrict__ epsw,
    u64* __restrict__ bestG)
{
    __shared__ __align__(16) float zx[32 * ZXP];  // recheck staging (2560 floats)
    __shared__ __align__(16) int cl[512];         // 16 pts x 32 candidate slots
    __shared__ float e2hS[1024];
    __shared__ unsigned int cntS[16];
    __shared__ int ovfS;

    const int tid = threadIdx.x;
    const int kq = tid >> 6;       // wave = K-quarter 0..3
    const int l  = tid & 63;
    const int lq = l >> 4;
    const int lr = l & 15;
    const int n0 = blockIdx.x << 4;      // 16 points per block
    const int zb = z_base(n0);

    if (tid < 16) cntS[tid] = 0u;
    if (tid == 0) ovfS = 0;
    for (int i = tid; i < 1024; i += 256) e2hS[i] = e2hw[i];

    // ---- A-fragments: direct global gather (64B-coalesced per 16-lane group) ----
    short8 af[8];
    {
        const float* zp = z + zb + lr;             // point = lr
#pragma unroll
        for (int dt = 0; dt < 8; ++dt)
#pragma unroll
            for (int j = 0; j < 8; ++j)
                af[dt][j] = (short)f2bf(zp[((dt << 5) + (lq << 3) + j) << 10]);
    }

    // per-lane filter state for the 4 points (lq*4+r) this lane owns in the C layout
    float4 epsv = *(const float4*)(epsw + n0 + (lq << 2));
    float eps_r[4] = { epsv.x, epsv.y, epsv.z, epsv.w };
    float Mr[4] = { -3.4e38f, -3.4e38f, -3.4e38f, -3.4e38f };

    __syncthreads();   // e2hS / cntS / ovfS visible to all waves

    // ---- register double-buffered B pipeline over this wave's K-quarter ----
    const ushort_t* fb = ebf + (l << 3);          // lane slot base
    const int ktg0 = kq << 3;                     // first 32-k tile of this quarter
    short8 B[2][2];                               // [parity][nt] — compile-time indices
    B[0][0] = *(const short8*)(fb + ((ktg0 * 16 + 0) << 9));
    B[0][1] = *(const short8*)(fb + ((ktg0 * 16 + 8) << 9));
    B[1][0] = *(const short8*)(fb + ((ktg0 * 16 + 1) << 9));
    B[1][1] = *(const short8*)(fb + ((ktg0 * 16 + 9) << 9));

    f32x4 acc[2];
#pragma unroll
    for (int nt = 0; nt < 2; ++nt) {
        float e = e2hS[(ktg0 << 5) + (nt << 4) + lr];
        f32x4 iv = { -e, -e, -e, -e };
        acc[nt] = iv;
    }

#pragma unroll 1
    for (int kt = 0; kt < 8; ++kt) {
        const int ktg = ktg0 + kt;
#pragma unroll
        for (int dt = 0; dt < 8; ++dt) {
            const int p = dt & 1;
            __builtin_amdgcn_s_setprio(1);
            acc[0] = __builtin_amdgcn_mfma_f32_16x16x32_bf16(af[dt], B[p][0], acc[0], 0, 0, 0);
            acc[1] = __builtin_amdgcn_mfma_f32_16x16x32_bf16(af[dt], B[p][1], acc[1], 0, 0, 0);
            __builtin_amdgcn_s_setprio(0);
            // prefetch step dt+2 (possibly next kt); &31 clamp = harmless unused tail
            const int ndt = (dt + 2) & 7;
            const int nktg = (dt >= 6) ? ((ktg + 1) & 31) : ktg;
            const int nf0 = nktg * 16 + ndt;
            B[p][0] = *(const short8*)(fb + (nf0 << 9));
            B[p][1] = *(const short8*)(fb + ((nf0 + 8) << 9));
        }
        // ---- filter: full 16-lane per-point running max + candidate record ----
        {
            float mx[4], thr[4];
#pragma unroll
            for (int r = 0; r < 4; ++r) mx[r] = fmaxf(acc[0][r], acc[1][r]);
#pragma unroll
            for (int s = 1; s <= 8; s <<= 1)
#pragma unroll
                for (int r = 0; r < 4; ++r)
                    mx[r] = fmaxf(mx[r], __shfl_xor(mx[r], s, 64));   // reduce over lr
#pragma unroll
            for (int r = 0; r < 4; ++r) {
                Mr[r] = fmaxf(Mr[r], mx[r]);
                thr[r] = Mr[r] - eps_r[r];   // running max <= final max -> superset, sound
            }
#pragma unroll
            for (int nt = 0; nt < 2; ++nt)
#pragma unroll
                for (int r = 0; r < 4; ++r) {
                    if (acc[nt][r] >= thr[r]) {
                        int pp = lq * 4 + r;
                        int kk = (ktg << 5) + (nt << 4) + lr;
                        unsigned int pos = atomicAdd(&cntS[pp], 1u);
                        if (pos < 32u) cl[pp * 32 + pos] = kk;
                        else atomicMax(&ovfS, 1);
                    }
                }
        }
        if (kt < 7) {   // re-init acc = -e2/2 for next tile
#pragma unroll
            for (int nt = 0; nt < 2; ++nt) {
                float e = e2hS[((ktg + 1) << 5) + (nt << 4) + lr];
                f32x4 iv = { -e, -e, -e, -e };
                acc[nt] = iv;
            }
        }
    }
    __syncthreads();   // all waves' candidates recorded

    // ---------------- exact recheck (bit-identical fp32 chain) ----------------
    const int pt = tid & 15;
    const int s0 = tid >> 4;                 // 16 slot-threads per point
    unsigned int nc = cntS[pt]; if (nc > 32u) nc = 32u;
    bool  act[2]; int kE[2]; float accE[2];
#pragma unroll
    for (int j = 0; j < 2; ++j) {
        unsigned int s = (unsigned int)s0 + 16u * j;
        act[j] = s < nc;
        kE[j] = act[j] ? cl[pt * 32 + s] : 0;
        accE[j] = 0.0f;
    }
#pragma unroll 1
    for (int dt = 0; dt < 8; ++dt) {
        const int dbase = dt * 32;
        __syncthreads();
        if (tid < 128) {                      // stage 16 pts x 32 dd
            int q = tid & 3, dd = tid >> 2;
            float4 v = *(const float4*)(z + zb + ((dbase + dd) << 10) + 4 * q);
            *(float4*)(zx + dd * ZXP + 4 * q) = v;
        }
        __syncthreads();
#pragma unroll
        for (int j = 0; j < 2; ++j) {
            if (!act[j]) continue;
            const float* er = emb + kE[j] * 256 + dbase;
            float ev[32];
#pragma unroll
            for (int c = 0; c < 8; ++c) *(float4*)(ev + 4 * c) = *(const float4*)(er + 4 * c);
            float a = accE[j];
#pragma unroll
            for (int dd = 0; dd < 32; ++dd)
                a = __builtin_fmaf(zx[dd * ZXP + pt], ev[dd], a);
            accE[j] = a;
        }
    }
#pragma unroll
    for (int j = 0; j < 2; ++j) {
        if (!act[j]) continue;
        int k = kE[j];
        float t1 = __fadd_rn(z2w[n0 + pt], e2w[k]);
        float d  = __fsub_rn(t1, __fmul_rn(2.0f, accE[j]));
        atomicMin(&bestG[n0 + pt], pack_vi(d, k));
    }
    __syncthreads();

    if (ovfS) {   // near-impossible fallback: full exact scan for overflowed points
        for (int row = 0; row < 16; ++row) {
            if (cntS[row] <= 32u) continue;
            float fa[4] = {0.f, 0.f, 0.f, 0.f};
            for (int dt = 0; dt < 8; ++dt) {
                const int dbase = dt * 32;
                __syncthreads();
                if (tid < 128) {
                    int q = tid & 3, dd = tid >> 2;
                    float4 v = *(const float4*)(z + zb + ((dbase + dd) << 10) + 4 * q);
                    *(float4*)(zx + dd * ZXP + 4 * q) = v;
                }
                __syncthreads();
                for (int c = 0; c < 4; ++c) {
                    const float* er = emb + (tid + 256 * c) * 256 + dbase;
                    for (int dd = 0; dd < 32; ++dd)
                        fa[c] = __builtin_fmaf(zx[dd * ZXP + row], er[dd], fa[c]);
                }
            }
            for (int c = 0; c < 4; ++c) {
                int k = tid + 256 * c;
                float t1 = __fadd_rn(z2w[n0 + row], e2w[k]);
                float d  = __fsub_rn(t1, __fmul_rn(2.0f, fa[c]));
                atomicMin(&bestG[n0 + row], pack_vi(d, k));
            }
            __syncthreads();
        }
    }
}

// 512 blocks: each block 64 points, d split in quarters across the four waves.
__global__ __launch_bounds__(256) void zq_loss_kernel(
    const float* __restrict__ z, const float* __restrict__ emb,
    const u64* __restrict__ bestG, float* __restrict__ zq,
    double* __restrict__ loss_acc, unsigned int* __restrict__ ticket,
    float* __restrict__ out_loss, float* __restrict__ out_idx)
{
    const int tl = threadIdx.x & 63;
    const int q  = threadIdx.x >> 6;         // d-quarter 0..3
    const int n  = blockIdx.x * 64 + tl;
    const int kk = (int)(u32)(bestG[n] & 0xFFFFFFFFULL);
    if (q == 0) out_idx[n] = (float)kk;
    const float4* er4 = (const float4*)(emb + kk * DIM + (q << 6));
    const int zb2 = z_base(n) + (q << 16);   // + (q*64)<<10
    double s = 0.0;
#pragma unroll 4
    for (int c = 0; c < 16; ++c) {
        float4 e4 = er4[c];
#pragma unroll
        for (int j = 0; j < 4; ++j) {
            int dd = c * 4 + j;
            float ev = (j == 0) ? e4.x : (j == 1) ? e4.y : (j == 2) ? e4.z : e4.w;
            float zv = z[zb2 + (dd << 10)];
            zq[zb2 + (dd << 10)] = ev;
            float df = ev - zv;
            s = fma((double)df, (double)df, s);
        }
    }
    for (int off = 32; off; off >>= 1) s += __shfl_down(s, off, 64);
    __shared__ double sred[4];
    if ((threadIdx.x & 63) == 0) sred[threadIdx.x >> 6] = s;
    __syncthreads();
    if (threadIdx.x == 0) {
        atomicAdd(loss_acc, (sred[0] + sred[1]) + (sred[2] + sred[3]));
        __threadfence();
        unsigned int old = atomicAdd(ticket, 1u);
        if (old == gridDim.x - 1) {
            double total = atomicAdd(loss_acc, 0.0);
            out_loss[0] = (float)(1.25 * (total / 8388608.0));
        }
    }
}

extern "C" void kernel_launch(void* const* d_in, const int* in_sizes, int n_in,
                              void* d_out, int out_size, void* d_ws, size_t ws_size,
                              hipStream_t stream) {
    const float* z   = (const float*)d_in[0];
    const float* emb = (const float*)d_in[1];
    float* out = (float*)d_out;

    // ws: z2[32768]f32 @0 | eps[32768]f32 @131072 | e2[1024] @262144 |
    //     e2h[1024] @266240 | ebf16(fragment-tiled image) @270336 (512KB) |
    //     loss f64 @794624 | ticket @794632 | bestG u64[32768] @794640
    float* z2w = (float*)d_ws;
    float* epsw = (float*)((char*)d_ws + 131072);
    float* e2w = (float*)((char*)d_ws + 262144);
    float* e2hw = (float*)((char*)d_ws + 266240);
    ushort_t* ebf = (ushort_t*)((char*)d_ws + 270336);
    double* loss_acc = (double*)((char*)d_ws + 794624);
    unsigned int* ticket = (unsigned int*)((char*)d_ws + 794632);
    u64* bestG = (u64*)((char*)d_ws + 794640);

    setup_kernel<<<272, 256, 0, stream>>>(z, emb, z2w, epsw, e2w, e2hw, ebf,
                                          bestG, loss_acc, ticket);
    dist_kernel<<<NPTS / 16, 256, 0, stream>>>(z, emb, ebf, z2w, e2w, e2hw,
                                               epsw, bestG);
    zq_loss_kernel<<<NPTS / 64, 256, 0, stream>>>(z, emb, bestG, out + ZQ_OFF,
                                                  loss_acc, ticket,
                                                  out + LOSS_OFF, out + IDX_OFF);
}

// Round 9
// 261.307 us; speedup vs baseline: 1.7406x; 1.7406x over previous
//
#include <hip/hip_runtime.h>

#define NPTS  32768
#define DIM   256

#define ZQ_OFF   0
#define LOSS_OFF 8388608
#define IDX_OFF  8388609

typedef __attribute__((ext_vector_type(8))) short short8;
typedef __attribute__((ext_vector_type(4))) float f32x4;
typedef unsigned short ushort_t;
typedef unsigned int u32;
typedef unsigned long long u64;

#define ZXP 36   // zx row pad (floats): float4-aligned, 2-way-free bank pattern on reads

// z layout [B, D, H, W]: point n = b*1024 + h*32 + w ; elem (n,d) at b*262144 + d*1024 + hw
__device__ __forceinline__ int z_base(int n) { return ((n >> 10) << 18) | (n & 1023); }

// RNE float->bf16 (bits)
__device__ __forceinline__ ushort_t f2bf(float f) {
    u32 u = __float_as_uint(f);
    u += 0x7FFFu + ((u >> 16) & 1u);
    return (ushort_t)(u >> 16);
}

__device__ __forceinline__ u64 pack_vi(float v, int i) {
    u32 u = __float_as_uint(v);
    u32 key = (u & 0x80000000u) ? ~u : u;   // monotone float->uint (finite)
    return ((u64)key << 32) | (u32)i;
}

// ---- numpy pairwise sum (AVX512 npyv order) of squares, 128 elems ----
__device__ __forceinline__ float np_half_sq(const float* __restrict__ p, int stride) {
    float S[16];
#pragma unroll
    for (int l = 0; l < 16; ++l) {
        float t[8];
#pragma unroll
        for (int j = 0; j < 8; ++j) {
            float v = p[(j * 16 + l) * stride];
            t[j] = __fmul_rn(v, v);
        }
        S[l] = __fadd_rn(__fadd_rn(__fadd_rn(t[0], t[1]), __fadd_rn(t[2], t[3])),
                         __fadd_rn(__fadd_rn(t[4], t[5]), __fadd_rn(t[6], t[7])));
    }
    float u[8];
#pragma unroll
    for (int i = 0; i < 8; ++i) u[i] = __fadd_rn(S[i], S[i + 8]);
    float v4[4];
#pragma unroll
    for (int i = 0; i < 4; ++i) v4[i] = __fadd_rn(u[i], u[i + 4]);
    return __fadd_rn(__fadd_rn(v4[0], v4[2]), __fadd_rn(v4[1], v4[3]));
}
__device__ __forceinline__ float np_sum256_sq(const float* __restrict__ p, int stride) {
    return __fadd_rn(np_half_sq(p, stride), np_half_sq(p + 128 * stride, stride));
}

// same square chain (bit-identical half-sum), abs-sum fused (order-free bound input)
__device__ __forceinline__ float np_half_sq_abs(const float* __restrict__ p, int stride, float* aacc) {
    float S[16]; float a = *aacc;
#pragma unroll
    for (int l = 0; l < 16; ++l) {
        float t[8];
#pragma unroll
        for (int j = 0; j < 8; ++j) {
            float v = p[(j * 16 + l) * stride];
            t[j] = __fmul_rn(v, v);
            a = __fadd_rn(a, fabsf(v));
        }
        S[l] = __fadd_rn(__fadd_rn(__fadd_rn(t[0], t[1]), __fadd_rn(t[2], t[3])),
                         __fadd_rn(__fadd_rn(t[4], t[5]), __fadd_rn(t[6], t[7])));
    }
    float u[8];
#pragma unroll
    for (int i = 0; i < 8; ++i) u[i] = __fadd_rn(S[i], S[i + 8]);
    float v4[4];
#pragma unroll
    for (int i = 0; i < 4; ++i) v4[i] = __fadd_rn(u[i], u[i + 4]);
    *aacc = a;
    return __fadd_rn(__fadd_rn(v4[0], v4[2]), __fadd_rn(v4[1], v4[3]));
}

// blocks 0..255: z2/eps/bestG, 128 points per block, one thread per point (full np chain).
// blocks 256..271: e2/e2h + FRAGMENT-TILED bf16 image of emb:
//   fragment f = kt*16 + nt*8 + dt is a 1KB block; slot l holds
//   bf16 emb[kt*32+nt*16+(l&15)][dt*32+(l>>4)*8 .. +7] at f*1024 + l*16.
__global__ __launch_bounds__(256) void setup_kernel(
    const float* __restrict__ z, const float* __restrict__ emb,
    float* __restrict__ z2, float* __restrict__ eps,
    float* __restrict__ e2, float* __restrict__ e2h,
    ushort_t* __restrict__ ebf, u64* __restrict__ bestG,
    double* __restrict__ loss_acc, unsigned int* __restrict__ ticket)
{
    if (blockIdx.x < 256) {
        if (threadIdx.x < 128) {
            int n = blockIdx.x * 128 + threadIdx.x;
            const float* p = z + z_base(n);
            float a = 0.0f;
            float h0 = np_half_sq_abs(p, 1024, &a);
            float h1 = np_half_sq_abs(p + 128 * 1024, 1024, &a);
            z2[n] = __fadd_rn(h0, h1);
            eps[n] = __builtin_fmaf(1e-5f, a, 3e-4f);   // sound |d~ - d| bound
            bestG[n] = 0x7FFFFFFFFFFFFFFFULL;
        }
        if (blockIdx.x == 0 && threadIdx.x == 0) { *loss_acc = 0.0; *ticket = 0u; }
    } else {
        int kb = (blockIdx.x - 256) * 64;                // 64 emb rows per block
        for (int i = threadIdx.x; i < 2048; i += 256) {
            int klocal = i >> 5, c = i & 31;             // c = dt*4 + lq
            int k = kb + klocal;
            int dt = c >> 2, lq = c & 3;
            int kt = k >> 5, nt = (k >> 4) & 1, lr = k & 15;
            const float* e = emb + k * 256 + dt * 32 + lq * 8;
            short8 ov;
#pragma unroll
            for (int j = 0; j < 8; ++j) ov[j] = (short)f2bf(e[j]);
            int f = kt * 16 + nt * 8 + dt;
            *(short8*)(ebf + (f << 9) + ((lq << 4) + lr) * 8) = ov;
        }
        if (threadIdx.x < 64) {
            int k = kb + threadIdx.x;
            float s = np_sum256_sq(emb + k * DIM, 1);
            e2[k] = s;
            e2h[k] = 0.5f * s;
        }
    }
}

// ---------------- MFMA distance + candidate filter + exact recheck ----------------
// 1024 blocks: 32 pts each. Wave w = (ph, kh): ph = w&1 point-half (16 pts), kh = w>>1
// K-half (512 k). 4 blocks/CU -> 16 waves/CU (vs R6's 8). Barrier-free, LDS-free main
// loop; A gathered once (32 VGPR); B direct global->VGPR, prefetch DEPTH 4 (slot dt&3
// self-double-buffers across kt: consume B[dt&3], then load step dt+4 into it).
// 2-climber filter (one per K-half) validated by R7: thr_local <= thr_global -> superset.
__global__ __launch_bounds__(256, 4) void dist_kernel(
    const float* __restrict__ z, const float* __restrict__ emb,
    const ushort_t* __restrict__ ebf,
    const float* __restrict__ z2w, const float* __restrict__ e2w,
    const float* __restrict__ e2hw, const float* __restrict__ epsw,
    u64* __restrict__ bestG)
{
    __shared__ __align__(16) float zx[32 * ZXP];  // recheck staging
    __shared__ __align__(16) int cl[1024];        // 32 pts x 32 candidate slots
    __shared__ float e2hS[1024];
    __shared__ unsigned int cntS[32];
    __shared__ int ovfS;

    const int tid = threadIdx.x;
    const int w  = tid >> 6;
    const int ph = w & 1;          // point-half (16 pts)
    const int kh = w >> 1;         // K-half (512 k)
    const int l  = tid & 63;
    const int lq = l >> 4;
    const int lr = l & 15;
    const int n0 = blockIdx.x << 5;      // 32 points per block
    const int zb = z_base(n0);
    const int pb = ph << 4;

    if (tid < 32) cntS[tid] = 0u;
    if (tid == 0) ovfS = 0;
    for (int i = tid; i < 1024; i += 256) e2hS[i] = e2hw[i];

    // ---- A-fragments: direct global gather (64B-coalesced per 16-lane group) ----
    short8 af[8];
    {
        const float* zp = z + zb + pb + lr;
#pragma unroll
        for (int dt = 0; dt < 8; ++dt)
#pragma unroll
            for (int j = 0; j < 8; ++j)
                af[dt][j] = (short)f2bf(zp[((dt << 5) + (lq << 3) + j) << 10]);
    }

    // per-lane filter state for the 4 points (pb + lq*4+r) this lane owns in C layout
    float4 epsv = *(const float4*)(epsw + n0 + pb + (lq << 2));
    float eps_r[4] = { epsv.x, epsv.y, epsv.z, epsv.w };
    float Mr[4] = { -3.4e38f, -3.4e38f, -3.4e38f, -3.4e38f };

    __syncthreads();   // e2hS / cntS / ovfS visible to all waves

    // ---- register B pipeline over this wave's K-half, prefetch depth 4 ----
    const ushort_t* fb = ebf + (l << 3);          // lane slot base
    const int ktg0 = kh << 4;                     // first 32-k tile of this half
    short8 B[4][2];                               // [dt&3][nt] — compile-time indices
#pragma unroll
    for (int i = 0; i < 4; ++i) {                 // preload steps dt=0..3 of kt0
        const int f0 = ktg0 * 16 + i;
        B[i][0] = *(const short8*)(fb + (f0 << 9));
        B[i][1] = *(const short8*)(fb + ((f0 + 8) << 9));
    }

    f32x4 acc[2];
#pragma unroll
    for (int nt = 0; nt < 2; ++nt) {
        float e = e2hS[(ktg0 << 5) + (nt << 4) + lr];
        f32x4 iv = { -e, -e, -e, -e };
        acc[nt] = iv;
    }

#pragma unroll 1
    for (int kt = 0; kt < 16; ++kt) {
        const int ktg = ktg0 + kt;
#pragma unroll
        for (int dt = 0; dt < 8; ++dt) {
            const int p = dt & 3;
            __builtin_amdgcn_s_setprio(1);
            acc[0] = __builtin_amdgcn_mfma_f32_16x16x32_bf16(af[dt], B[p][0], acc[0], 0, 0, 0);
            acc[1] = __builtin_amdgcn_mfma_f32_16x16x32_bf16(af[dt], B[p][1], acc[1], 0, 0, 0);
            __builtin_amdgcn_s_setprio(0);
            // prefetch step dt+4 (next kt when dt>=4); &31 clamp = harmless unused tail
            const int ndt = (dt + 4) & 7;
            const int nktg = (dt >= 4) ? ((ktg + 1) & 31) : ktg;
            const int nf0 = nktg * 16 + ndt;
            B[p][0] = *(const short8*)(fb + (nf0 << 9));
            B[p][1] = *(const short8*)(fb + ((nf0 + 8) << 9));
        }
        // ---- filter: full 16-lane per-point running max + candidate record ----
        {
            float mx[4], thr[4];
#pragma unroll
            for (int r = 0; r < 4; ++r) mx[r] = fmaxf(acc[0][r], acc[1][r]);
#pragma unroll
            for (int s = 1; s <= 8; s <<= 1)
#pragma unroll
                for (int r = 0; r < 4; ++r)
                    mx[r] = fmaxf(mx[r], __shfl_xor(mx[r], s, 64));   // reduce over lr
#pragma unroll
            for (int r = 0; r < 4; ++r) {
                Mr[r] = fmaxf(Mr[r], mx[r]);
                thr[r] = Mr[r] - eps_r[r];   // running max <= final max -> superset, sound
            }
#pragma unroll
            for (int nt = 0; nt < 2; ++nt)
#pragma unroll
                for (int r = 0; r < 4; ++r) {
                    if (acc[nt][r] >= thr[r]) {
                        int pp = pb + lq * 4 + r;
                        int kk = (ktg << 5) + (nt << 4) + lr;
                        unsigned int pos = atomicAdd(&cntS[pp], 1u);
                        if (pos < 32u) cl[pp * 32 + pos] = kk;
                        else atomicMax(&ovfS, 1);
                    }
                }
        }
        if (kt < 15) {   // re-init acc = -e2/2 for next tile
#pragma unroll
            for (int nt = 0; nt < 2; ++nt) {
                float e = e2hS[((ktg + 1) << 5) + (nt << 4) + lr];
                f32x4 iv = { -e, -e, -e, -e };
                acc[nt] = iv;
            }
        }
    }
    __syncthreads();   // all waves' candidates recorded

    // ---------------- exact recheck (bit-identical fp32 chain) ----------------
    const int pt = tid & 31;
    const int s0 = tid >> 5;                 // 8 slot-threads per point
    unsigned int nc = cntS[pt]; if (nc > 32u) nc = 32u;
    bool  act[4]; int kE[4]; float accE[4];
#pragma unroll
    for (int j = 0; j < 4; ++j) {
        unsigned int s = (unsigned int)s0 + 8u * j;
        act[j] = s < nc;
        kE[j] = act[j] ? cl[pt * 32 + s] : 0;
        accE[j] = 0.0f;
    }
#pragma unroll 1
    for (int dt = 0; dt < 8; ++dt) {
        const int dbase = dt * 32;
        __syncthreads();
        {                                     // stage 32 pts x 32 dd (full block)
            int q = tid & 7, dd = tid >> 3;
            float4 v = *(const float4*)(z + zb + ((dbase + dd) << 10) + 4 * q);
            *(float4*)(zx + dd * ZXP + 4 * q) = v;
        }
        __syncthreads();
#pragma unroll
        for (int j = 0; j < 4; ++j) {
            if (!act[j]) continue;
            const float* er = emb + kE[j] * 256 + dbase;
            float ev[32];
#pragma unroll
            for (int c = 0; c < 8; ++c) *(float4*)(ev + 4 * c) = *(const float4*)(er + 4 * c);
            float a = accE[j];
#pragma unroll
            for (int dd = 0; dd < 32; ++dd)
                a = __builtin_fmaf(zx[dd * ZXP + pt], ev[dd], a);
            accE[j] = a;
        }
    }
#pragma unroll
    for (int j = 0; j < 4; ++j) {
        if (!act[j]) continue;
        int k = kE[j];
        float t1 = __fadd_rn(z2w[n0 + pt], e2w[k]);
        float d  = __fsub_rn(t1, __fmul_rn(2.0f, accE[j]));
        atomicMin(&bestG[n0 + pt], pack_vi(d, k));
    }
    __syncthreads();

    if (ovfS) {   // near-impossible fallback: full exact scan for overflowed points
        for (int row = 0; row < 32; ++row) {
            if (cntS[row] <= 32u) continue;
            float fa[4] = {0.f, 0.f, 0.f, 0.f};
            for (int dt = 0; dt < 8; ++dt) {
                const int dbase = dt * 32;
                __syncthreads();
                {
                    int q = tid & 7, dd = tid >> 3;
                    float4 v = *(const float4*)(z + zb + ((dbase + dd) << 10) + 4 * q);
                    *(float4*)(zx + dd * ZXP + 4 * q) = v;
                }
                __syncthreads();
                for (int c = 0; c < 4; ++c) {
                    const float* er = emb + (tid + 256 * c) * 256 + dbase;
                    for (int dd = 0; dd < 32; ++dd)
                        fa[c] = __builtin_fmaf(zx[dd * ZXP + row], er[dd], fa[c]);
                }
            }
            for (int c = 0; c < 4; ++c) {
                int k = tid + 256 * c;
                float t1 = __fadd_rn(z2w[n0 + row], e2w[k]);
                float d  = __fsub_rn(t1, __fmul_rn(2.0f, fa[c]));
                atomicMin(&bestG[n0 + row], pack_vi(d, k));
            }
            __syncthreads();
        }
    }
}

// 512 blocks: each block 64 points, d split in quarters across the four waves.
__global__ __launch_bounds__(256) void zq_loss_kernel(
    const float* __restrict__ z, const float* __restrict__ emb,
    const u64* __restrict__ bestG, float* __restrict__ zq,
    double* __restrict__ loss_acc, unsigned int* __restrict__ ticket,
    float* __restrict__ out_loss, float* __restrict__ out_idx)
{
    const int tl = threadIdx.x & 63;
    const int q  = threadIdx.x >> 6;         // d-quarter 0..3
    const int n  = blockIdx.x * 64 + tl;
    const int kk = (int)(u32)(bestG[n] & 0xFFFFFFFFULL);
    if (q == 0) out_idx[n] = (float)kk;
    const float4* er4 = (const float4*)(emb + kk * DIM + (q << 6));
    const int zb2 = z_base(n) + (q << 16);   // + (q*64)<<10
    double s = 0.0;
#pragma unroll 4
    for (int c = 0; c < 16; ++c) {
        float4 e4 = er4[c];
#pragma unroll
        for (int j = 0; j < 4; ++j) {
            int dd = c * 4 + j;
            float ev = (j == 0) ? e4.x : (j == 1) ? e4.y : (j == 2) ? e4.z : e4.w;
            float zv = z[zb2 + (dd << 10)];
            zq[zb2 + (dd << 10)] = ev;
            float df = ev - zv;
            s = fma((double)df, (double)df, s);
        }
    }
    for (int off = 32; off; off >>= 1) s += __shfl_down(s, off, 64);
    __shared__ double sred[4];
    if ((threadIdx.x & 63) == 0) sred[threadIdx.x >> 6] = s;
    __syncthreads();
    if (threadIdx.x == 0) {
        atomicAdd(loss_acc, (sred[0] + sred[1]) + (sred[2] + sred[3]));
        __threadfence();
        unsigned int old = atomicAdd(ticket, 1u);
        if (old == gridDim.x - 1) {
            double total = atomicAdd(loss_acc, 0.0);
            out_loss[0] = (float)(1.25 * (total / 8388608.0));
        }
    }
}

extern "C" void kernel_launch(void* const* d_in, const int* in_sizes, int n_in,
                              void* d_out, int out_size, void* d_ws, size_t ws_size,
                              hipStream_t stream) {
    const float* z   = (const float*)d_in[0];
    const float* emb = (const float*)d_in[1];
    float* out = (float*)d_out;

    // ws: z2[32768]f32 @0 | eps[32768]f32 @131072 | e2[1024] @262144 |
    //     e2h[1024] @266240 | ebf16(fragment-tiled image) @270336 (512KB) |
    //     loss f64 @794624 | ticket @794632 | bestG u64[32768] @794640
    float* z2w = (float*)d_ws;
    float* epsw = (float*)((char*)d_ws + 131072);
    float* e2w = (float*)((char*)d_ws + 262144);
    float* e2hw = (float*)((char*)d_ws + 266240);
    ushort_t* ebf = (ushort_t*)((char*)d_ws + 270336);
    double* loss_acc = (double*)((char*)d_ws + 794624);
    unsigned int* ticket = (unsigned int*)((char*)d_ws + 794632);
    u64* bestG = (u64*)((char*)d_ws + 794640);

    setup_kernel<<<272, 256, 0, stream>>>(z, emb, z2w, epsw, e2w, e2hw, ebf,
                                          bestG, loss_acc, ticket);
    dist_kernel<<<NPTS / 32, 256, 0, stream>>>(z, emb, ebf, z2w, e2w, e2hw,
                                               epsw, bestG);
    zq_loss_kernel<<<NPTS / 64, 256, 0, stream>>>(z, emb, bestG, out + ZQ_OFF,
                                                  loss_acc, ticket,
                                                  out + LOSS_OFF, out + IDX_OFF);
}

// Round 10
// 201.976 us; speedup vs baseline: 2.2519x; 1.2937x over previous
//
#include <hip/hip_runtime.h>

#define NPTS  32768
#define DIM   256

#define ZQ_OFF   0
#define LOSS_OFF 8388608
#define IDX_OFF  8388609

typedef __attribute__((ext_vector_type(8))) short short8;
typedef __attribute__((ext_vector_type(4))) float f32x4;
typedef unsigned short ushort_t;
typedef unsigned int u32;
typedef unsigned long long u64;

// z layout [B, D, H, W]: point n = b*1024 + h*32 + w ; elem (n,d) at b*262144 + d*1024 + hw
__device__ __forceinline__ int z_base(int n) { return ((n >> 10) << 18) | (n & 1023); }

// RNE float->bf16 (bits)
__device__ __forceinline__ ushort_t f2bf(float f) {
    u32 u = __float_as_uint(f);
    u += 0x7FFFu + ((u >> 16) & 1u);
    return (ushort_t)(u >> 16);
}

__device__ __forceinline__ u64 pack_vi(float v, int i) {
    u32 u = __float_as_uint(v);
    u32 key = (u & 0x80000000u) ? ~u : u;   // monotone float->uint (finite)
    return ((u64)key << 32) | (u32)i;
}

// ---- numpy pairwise sum (AVX512 npyv order) of squares, 128 elems ----
__device__ __forceinline__ float np_half_sq(const float* __restrict__ p, int stride) {
    float S[16];
#pragma unroll
    for (int l = 0; l < 16; ++l) {
        float t[8];
#pragma unroll
        for (int j = 0; j < 8; ++j) {
            float v = p[(j * 16 + l) * stride];
            t[j] = __fmul_rn(v, v);
        }
        S[l] = __fadd_rn(__fadd_rn(__fadd_rn(t[0], t[1]), __fadd_rn(t[2], t[3])),
                         __fadd_rn(__fadd_rn(t[4], t[5]), __fadd_rn(t[6], t[7])));
    }
    float u[8];
#pragma unroll
    for (int i = 0; i < 8; ++i) u[i] = __fadd_rn(S[i], S[i + 8]);
    float v4[4];
#pragma unroll
    for (int i = 0; i < 4; ++i) v4[i] = __fadd_rn(u[i], u[i + 4]);
    return __fadd_rn(__fadd_rn(v4[0], v4[2]), __fadd_rn(v4[1], v4[3]));
}
__device__ __forceinline__ float np_sum256_sq(const float* __restrict__ p, int stride) {
    return __fadd_rn(np_half_sq(p, stride), np_half_sq(p + 128 * stride, stride));
}

// same square chain (bit-identical half-sum), abs-sum fused (order-free bound input)
__device__ __forceinline__ float np_half_sq_abs(const float* __restrict__ p, int stride, float* aacc) {
    float S[16]; float a = *aacc;
#pragma unroll
    for (int l = 0; l < 16; ++l) {
        float t[8];
#pragma unroll
        for (int j = 0; j < 8; ++j) {
            float v = p[(j * 16 + l) * stride];
            t[j] = __fmul_rn(v, v);
            a = __fadd_rn(a, fabsf(v));
        }
        S[l] = __fadd_rn(__fadd_rn(__fadd_rn(t[0], t[1]), __fadd_rn(t[2], t[3])),
                         __fadd_rn(__fadd_rn(t[4], t[5]), __fadd_rn(t[6], t[7])));
    }
    float u[8];
#pragma unroll
    for (int i = 0; i < 8; ++i) u[i] = __fadd_rn(S[i], S[i + 8]);
    float v4[4];
#pragma unroll
    for (int i = 0; i < 4; ++i) v4[i] = __fadd_rn(u[i], u[i + 4]);
    *aacc = a;
    return __fadd_rn(__fadd_rn(v4[0], v4[2]), __fadd_rn(v4[1], v4[3]));
}

// 128 blocks: e2/e2h (8 rows/block) + FRAGMENT-TILED bf16 image of emb:
//   fragment f = kt*16 + nt*8 + dt is a 1KB block; slot l holds
//   bf16 emb[kt*32+nt*16+(l&15)][dt*32+(l>>4)*8 .. +7] at f*1024 + l*16.
// block 0 thread 0 also inits loss_acc/ticket.
__global__ __launch_bounds__(256) void setup_kernel(
    const float* __restrict__ emb,
    float* __restrict__ e2, float* __restrict__ e2h,
    ushort_t* __restrict__ ebf,
    double* __restrict__ loss_acc, unsigned int* __restrict__ ticket)
{
    int kb = blockIdx.x * 8;                       // 8 emb rows per block
    if (threadIdx.x < 256) {
        int i = threadIdx.x;                       // 8*32 = 256 items
        int klocal = i >> 5, c = i & 31;           // c = dt*4 + lq
        int k = kb + klocal;
        int dt = c >> 2, lq = c & 3;
        int kt = k >> 5, nt = (k >> 4) & 1, lr = k & 15;
        const float* e = emb + k * 256 + dt * 32 + lq * 8;
        short8 ov;
#pragma unroll
        for (int j = 0; j < 8; ++j) ov[j] = (short)f2bf(e[j]);
        int f = kt * 16 + nt * 8 + dt;
        *(short8*)(ebf + (f << 9) + ((lq << 4) + lr) * 8) = ov;
    }
    if (threadIdx.x < 8) {
        int k = kb + threadIdx.x;
        float s = np_sum256_sq(emb + k * DIM, 1);
        e2[k] = s;
        e2h[k] = 0.5f * s;
    }
    if (blockIdx.x == 0 && threadIdx.x == 0) { *loss_acc = 0.0; *ticket = 0u; }
}

// ---------------- fully-fused dist + filter + recheck + zq/loss/idx ----------------
// 512 blocks: 64 pts x full 1024 k; 4 waves each own 16 POINTS (mt=1) — R6's proven
// main loop verbatim. Fused per block (overlaps other blocks' main loops):
//   prologue: z2/eps computed in-block (bit-identical np chains, 2 threads/pt);
//   bestS in LDS (no global bestG round-trip);
//   epilogue: zq write + loss accumulation + idx write; ticket publishes loss.
__global__ __launch_bounds__(256, 2) void dist_kernel(
    const float* __restrict__ z, const float* __restrict__ emb,
    const ushort_t* __restrict__ ebf,
    const float* __restrict__ e2w, const float* __restrict__ e2hw,
    float* __restrict__ zq, float* __restrict__ out_idx,
    float* __restrict__ out_loss,
    double* __restrict__ loss_acc, unsigned int* __restrict__ ticket)
{
    __shared__ __align__(16) float zx[32 * 68];   // recheck staging (8704B)
    __shared__ __align__(16) int cl[2048];        // 64 pts x 32 slots; prologue hbuf/abuf alias
    __shared__ float e2hS[1024];
    __shared__ float z2S[64], epsS[64];
    __shared__ unsigned int cntS[64];
    __shared__ u64 bestS[64];
    __shared__ double sred[4];
    __shared__ int ovfS;

    const int tid = threadIdx.x;
    const int w  = tid >> 6;       // wave 0..3
    const int l  = tid & 63;
    const int lq = l >> 4;
    const int lr = l & 15;
    const int n0 = blockIdx.x << 6;
    const int zb = z_base(n0);
    const int pbase = w << 4;      // wave's 16-point base

    if (tid < 64) { cntS[tid] = 0u; bestS[tid] = 0x7FFFFFFFFFFFFFFFULL; }
    if (tid == 0) ovfS = 0;
    for (int i = tid; i < 1024; i += 256) e2hS[i] = e2hw[i];

    // ---- in-block z2/eps prologue: 2 threads per point (the two np halves) ----
    float* hbuf = (float*)cl;          // alias: cl candidate writes start after sync2
    float* abuf = hbuf + 64;
    float hs = 0.0f, aa = 0.0f;
    if (tid < 128) {
        const int tl = tid & 63, half = tid >> 6;
        aa = 0.0f;
        hs = np_half_sq_abs(z + zb + tl + (half << 17), 1024, &aa);
        if (half) { hbuf[tl] = hs; abuf[tl] = aa; }
    }
    __syncthreads();                   // sync1: hbuf/abuf ready
    if (tid < 64) {
        z2S[tid] = __fadd_rn(hs, hbuf[tid]);                     // exact np order h0+h1
        epsS[tid] = __builtin_fmaf(1e-5f, aa + abuf[tid], 3e-4f); // sound bound
    }

    // ---- A-fragments: direct global gather (64B-coalesced per 16-lane group) ----
    short8 af[8];
    {
        const float* zp = z + zb + pbase + lr;
#pragma unroll
        for (int dt = 0; dt < 8; ++dt)
#pragma unroll
            for (int j = 0; j < 8; ++j)
                af[dt][j] = (short)f2bf(zp[((dt << 5) + (lq << 3) + j) << 10]);
    }

    // ---- register double-buffered B pipeline, prefetch distance 2 (R6 verbatim) ----
    const ushort_t* fb = ebf + (l << 3);          // lane slot base
    short8 B[2][2];                               // [parity][nt] — compile-time indices
    B[0][0] = *(const short8*)(fb + (0 << 9));
    B[0][1] = *(const short8*)(fb + (8 << 9));
    B[1][0] = *(const short8*)(fb + (1 << 9));
    B[1][1] = *(const short8*)(fb + (9 << 9));

    __syncthreads();                   // sync2: z2S/epsS/e2hS/cntS/bestS visible

    // per-lane filter state for the 4 points (lq*4+r) this lane owns in the C layout
    float eps_r[4], Mr[4];
#pragma unroll
    for (int r = 0; r < 4; ++r) {
        eps_r[r] = epsS[pbase + lq * 4 + r];
        Mr[r] = -3.4e38f;
    }

    f32x4 acc[2];
#pragma unroll
    for (int nt = 0; nt < 2; ++nt) {
        float e = e2hS[(nt << 4) + lr];
        f32x4 iv = { -e, -e, -e, -e };
        acc[nt] = iv;
    }

#pragma unroll 1
    for (int kt = 0; kt < 32; ++kt) {
        const int kt1 = (kt < 31) ? kt + 1 : 0;   // kt=31 prefetch is a harmless dummy
#pragma unroll
        for (int dt = 0; dt < 8; ++dt) {
            const int p = dt & 1;
            __builtin_amdgcn_s_setprio(1);
            acc[0] = __builtin_amdgcn_mfma_f32_16x16x32_bf16(af[dt], B[p][0], acc[0], 0, 0, 0);
            acc[1] = __builtin_amdgcn_mfma_f32_16x16x32_bf16(af[dt], B[p][1], acc[1], 0, 0, 0);
            __builtin_amdgcn_s_setprio(0);
            const int dtn = dt + 2;
            const int fk = (dtn < 8) ? kt : kt1;
            const int f0 = fk * 16 + (dtn & 7);
            B[p][0] = *(const short8*)(fb + (f0 << 9));
            B[p][1] = *(const short8*)(fb + ((f0 + 8) << 9));
        }
        // ---- filter: full 16-lane per-point running max + candidate record ----
        {
            float mx[4], thr[4];
#pragma unroll
            for (int r = 0; r < 4; ++r) mx[r] = fmaxf(acc[0][r], acc[1][r]);
#pragma unroll
            for (int s = 1; s <= 8; s <<= 1)
#pragma unroll
                for (int r = 0; r < 4; ++r)
                    mx[r] = fmaxf(mx[r], __shfl_xor(mx[r], s, 64));   // reduce over lr
#pragma unroll
            for (int r = 0; r < 4; ++r) {
                Mr[r] = fmaxf(Mr[r], mx[r]);
                thr[r] = Mr[r] - eps_r[r];   // running max <= final max -> superset, sound
            }
#pragma unroll
            for (int nt = 0; nt < 2; ++nt)
#pragma unroll
                for (int r = 0; r < 4; ++r) {
                    if (acc[nt][r] >= thr[r]) {
                        int pp = pbase + lq * 4 + r;
                        int kk = (kt << 5) + (nt << 4) + lr;
                        unsigned int pos = atomicAdd(&cntS[pp], 1u);
                        if (pos < 32u) cl[pp * 32 + pos] = kk;
                        else atomicMax(&ovfS, 1);
                    }
                }
        }
        if (kt < 31) {   // re-init acc = -e2/2 for next tile
#pragma unroll
            for (int nt = 0; nt < 2; ++nt) {
                float e = e2hS[(kt1 << 5) + (nt << 4) + lr];
                f32x4 iv = { -e, -e, -e, -e };
                acc[nt] = iv;
            }
        }
    }
    __syncthreads();   // all waves' candidates recorded

    // ---------------- exact recheck (bit-identical fp32 chain) ----------------
    const int pt = tid & 63;
    const int s0 = tid >> 6;                 // 4 slot-threads per point
    unsigned int nc = cntS[pt]; if (nc > 32u) nc = 32u;
    bool  act[8]; int kE[8]; float accE[8];
#pragma unroll
    for (int j = 0; j < 8; ++j) {
        unsigned int s = (unsigned int)s0 + 4u * j;
        act[j] = s < nc;
        kE[j] = act[j] ? cl[pt * 32 + s] : 0;
        accE[j] = 0.0f;
    }
#pragma unroll 1
    for (int dt = 0; dt < 8; ++dt) {
        const int dbase = dt * 32;
        __syncthreads();
        {
            int q = tid & 15, dd0 = tid >> 4;
            float4 v0 = *(const float4*)(z + zb + ((dbase + dd0) << 10) + 4 * q);
            float4 v1 = *(const float4*)(z + zb + ((dbase + dd0 + 16) << 10) + 4 * q);
            *(float4*)(zx + dd0 * 68 + 4 * q) = v0;
            *(float4*)(zx + (dd0 + 16) * 68 + 4 * q) = v1;
        }
        __syncthreads();
#pragma unroll
        for (int j = 0; j < 8; ++j) {
            if (!act[j]) continue;
            const float* er = emb + kE[j] * 256 + dbase;
            float ev[32];
#pragma unroll
            for (int c = 0; c < 8; ++c) *(float4*)(ev + 4 * c) = *(const float4*)(er + 4 * c);
            float a = accE[j];
#pragma unroll
            for (int dd = 0; dd < 32; ++dd)
                a = __builtin_fmaf(zx[dd * 68 + pt], ev[dd], a);
            accE[j] = a;
        }
    }
#pragma unroll
    for (int j = 0; j < 8; ++j) {
        if (!act[j]) continue;
        int k = kE[j];
        float t1 = __fadd_rn(z2S[pt], e2w[k]);
        float d  = __fsub_rn(t1, __fmul_rn(2.0f, accE[j]));
        atomicMin(&bestS[pt], pack_vi(d, k));
    }
    __syncthreads();

    if (ovfS) {   // near-impossible fallback: full exact scan for overflowed points
        for (int row = 0; row < 64; ++row) {
            if (cntS[row] <= 32u) continue;
            float fa[4] = {0.f, 0.f, 0.f, 0.f};
            for (int dt = 0; dt < 8; ++dt) {
                const int dbase = dt * 32;
                __syncthreads();
                {
                    int q = tid & 15, dd0 = tid >> 4;
                    float4 v0 = *(const float4*)(z + zb + ((dbase + dd0) << 10) + 4 * q);
                    float4 v1 = *(const float4*)(z + zb + ((dbase + dd0 + 16) << 10) + 4 * q);
                    *(float4*)(zx + dd0 * 68 + 4 * q) = v0;
                    *(float4*)(zx + (dd0 + 16) * 68 + 4 * q) = v1;
                }
                __syncthreads();
                for (int c = 0; c < 4; ++c) {
                    const float* er = emb + (tid + 256 * c) * 256 + dbase;
                    for (int dd = 0; dd < 32; ++dd)
                        fa[c] = __builtin_fmaf(zx[dd * 68 + row], er[dd], fa[c]);
                }
            }
            for (int c = 0; c < 4; ++c) {
                int k = tid + 256 * c;
                float t1 = __fadd_rn(z2S[row], e2w[k]);
                float d  = __fsub_rn(t1, __fmul_rn(2.0f, fa[c]));
                atomicMin(&bestS[row], pack_vi(d, k));
            }
            __syncthreads();
        }
    }
    __syncthreads();   // bestS final

    // ---------------- fused epilogue: zq write + loss + idx ----------------
    {
        const int tl = tid & 63;
        const int q  = tid >> 6;             // d-quarter 0..3
        const int kk = (int)(u32)(bestS[tl] & 0xFFFFFFFFULL);
        if (q == 0) out_idx[n0 + tl] = (float)kk;
        const float4* er4 = (const float4*)(emb + kk * DIM + (q << 6));
        const int zb2 = zb + tl + (q << 16); // z_base(n0+tl) + (q*64)<<10
        double s = 0.0;
#pragma unroll 4
        for (int c = 0; c < 16; ++c) {
            float4 e4 = er4[c];
#pragma unroll
            for (int j = 0; j < 4; ++j) {
                int dd = c * 4 + j;
                float ev = (j == 0) ? e4.x : (j == 1) ? e4.y : (j == 2) ? e4.z : e4.w;
                float zv = z[zb2 + (dd << 10)];
                zq[zb2 + (dd << 10)] = ev;
                float df = ev - zv;
                s = fma((double)df, (double)df, s);
            }
        }
        for (int off = 32; off; off >>= 1) s += __shfl_down(s, off, 64);
        if ((tid & 63) == 0) sred[tid >> 6] = s;
        __syncthreads();
        if (tid == 0) {
            atomicAdd(loss_acc, (sred[0] + sred[1]) + (sred[2] + sred[3]));
            __threadfence();
            unsigned int old = atomicAdd(ticket, 1u);
            if (old == gridDim.x - 1) {
                double total = atomicAdd(loss_acc, 0.0);
                out_loss[0] = (float)(1.25 * (total / 8388608.0));
            }
        }
    }
}

extern "C" void kernel_launch(void* const* d_in, const int* in_sizes, int n_in,
                              void* d_out, int out_size, void* d_ws, size_t ws_size,
                              hipStream_t stream) {
    const float* z   = (const float*)d_in[0];
    const float* emb = (const float*)d_in[1];
    float* out = (float*)d_out;

    // ws: e2[1024] @262144 | e2h[1024] @266240 | ebf16(fragment-tiled) @270336 (512KB) |
    //     loss f64 @794624 | ticket @794632
    float* e2w = (float*)((char*)d_ws + 262144);
    float* e2hw = (float*)((char*)d_ws + 266240);
    ushort_t* ebf = (ushort_t*)((char*)d_ws + 270336);
    double* loss_acc = (double*)((char*)d_ws + 794624);
    unsigned int* ticket = (unsigned int*)((char*)d_ws + 794632);

    setup_kernel<<<128, 256, 0, stream>>>(emb, e2w, e2hw, ebf, loss_acc, ticket);
    dist_kernel<<<NPTS / 64, 256, 0, stream>>>(z, emb, ebf, e2w, e2hw,
                                               out + ZQ_OFF, out + IDX_OFF,
                                               out + LOSS_OFF, loss_acc, ticket);
}